// Round 18
// baseline (109.563 us; speedup 1.0000x reference)
//
#include <hip/hip_runtime.h>
#include <cstdint>
#include <cstddef>

#define B_ 256
#define IW_ 3072
#define L_ 8
#define NN_ 7
#define FCIN_ 16384
#define OUTW_ 10
#define ICST 72            // ushorts per (row,col) cell: 64 ic + 8 pad
#define YPLANE (324 * ICST)   // 23328 us = 46.7 KB
#define WCH 36864          // ushorts per leaf W2 chunk: [icc2][tap9][mt4][lane64][j8] single RTN plane = 72 KB

typedef short short8 __attribute__((ext_vector_type(8)));
typedef float f32x4 __attribute__((ext_vector_type(4)));

__device__ __forceinline__ ushort f2bf(float x) {
    uint u = __float_as_uint(x);
    return (ushort)((u + 0x7fffu + ((u >> 16) & 1u)) >> 16);
}
__device__ __forceinline__ float bf2f(ushort b) { return __uint_as_float(((uint)b) << 16); }

// ---------- merged prep ----------
// [0,64): w1 repack | [64,1216): w2 repack | [1216,1984): fcw transpose | [1984,2240): mixture
__global__ __launch_bounds__(256) void k_prep(const float* __restrict__ w1, ushort* __restrict__ w1fr,
                                              const float* __restrict__ w2, ushort* __restrict__ w2r,
                                              const float* __restrict__ fcw, float* __restrict__ fcwT,
                                              const float* __restrict__ x, const float* __restrict__ nw,
                                              const float* __restrict__ nb, float* __restrict__ mix) {
    int blk = blockIdx.x;
    if (blk < 64) {
        int i = blk * 256 + threadIdx.x;
        int j    = i & 7;
        int lane = (i >> 3) & 63;
        int mt   = (i >> 9) & 3;
        int l    = i >> 11;
        int fr = lane & 15, fq = lane >> 4;
        int oc = mt * 16 + fr;
        int k = fq * 8 + j;
        float w = (k < 27) ? w1[(size_t)(l * 64 + oc) * 27 + k] : 0.f;
        w1fr[i] = f2bf(w);
        return;
    }
    if (blk < 1216) {
        int i = (blk - 64) * 256 + threadIdx.x;
        int j     = i & 7;
        int lane  = (i >> 3) & 63;
        int mt    = (i >> 9) & 3;
        int tap   = (i >> 11) % 9;
        int icc   = (i / 18432) & 1;
        int l     = i / 36864;
        int fr = lane & 15, fq = lane >> 4;
        int oc = mt * 16 + fr;
        int ic = icc * 32 + fq * 8 + j;
        float w = w2[(((size_t)l * 64 + oc) * 64 + ic) * 9 + tap];
        w2r[i] = f2bf(w);
        return;
    }
    if (blk < 1984) {
        // fcwT[e][12]: j<10 -> fcw[j][e], else 0 (pad for 48B-aligned b128 loads)
        int i = (blk - 1216) * 256 + threadIdx.x;   // 0..196607
        int e = i / 12, j = i - e * 12;
        fcwT[i] = (j < OUTW_) ? fcw[(size_t)j * FCIN_ + e] : 0.f;
        return;
    }
    // mixture
    __shared__ float red[4 * NN_];
    __shared__ float bes[NN_];
    int b = blk - 1984, tid = threadIdx.x;
    const float* xb = x + (size_t)b * IW_;
    float p[NN_];
#pragma unroll
    for (int n = 0; n < NN_; ++n) p[n] = 0.f;
    for (int i = tid; i < IW_; i += 256) {
        float xv = xb[i];
#pragma unroll
        for (int n = 0; n < NN_; ++n) p[n] = fmaf(xv, nw[n * IW_ + i], p[n]);
    }
#pragma unroll
    for (int n = 0; n < NN_; ++n) {
        float v = p[n];
        for (int off = 32; off > 0; off >>= 1) v += __shfl_xor(v, off);
        if ((tid & 63) == 0) red[(tid >> 6) * NN_ + n] = v;
    }
    __syncthreads();
    if (tid < NN_) {
        float s = red[tid] + red[NN_ + tid] + red[2 * NN_ + tid] + red[3 * NN_ + tid] + nb[tid];
        bes[tid] = 1.f / (1.f + expf(-s));
    }
    __syncthreads();
    if (tid < L_) {
        int leaf = tid;
        float b0 = bes[0];
        float t0 = ((leaf >> 2) & 1) ? b0 : 1.f - b0;
        float b1v = bes[1 + ((leaf >> 2) & 1)];
        float t1 = ((leaf >> 1) & 1) ? b1v : 1.f - b1v;
        float b2v = bes[3 + ((leaf >> 1) & 3)];
        float t2 = (leaf & 1) ? b2v : 1.f - b2v;
        mix[b * L_ + leaf] = t0 * t1 * t2;
    }
}

// ---------- fused conv1/conv2/fc: full-leaf steps + block-local fc epilogue ----------
// block = sample (grid 256 = 1/CU), 512 thr / 8 waves, 8 steps (one per leaf).
// After the leaf loop each thread holds its 32 out1 elements in oacc; fc is computed
// block-locally (fcwT 3xb128 per element) + shfl/LDS reduce -> out[b][10]. No out1 in HBM.
__global__ __launch_bounds__(512, 1) void k_fused(const float* __restrict__ x,
                                                  const ushort* __restrict__ w1fr,
                                                  const float* __restrict__ cb1,
                                                  const ushort* __restrict__ w2r,
                                                  const float* __restrict__ cb2, const float* __restrict__ mixw,
                                                  const float* __restrict__ fcwT, const float* __restrict__ fcb,
                                                  float* __restrict__ out, int boff) {
    __shared__ __align__(16) ushort smem[YPLANE + WCH];   // yt 46.7 KB | wlds 72 KB = 117.6 KB
    ushort* yt = smem;
    ushort* wlds = smem + YPLANE;
    float* xpad = (float*)smem;                            // prologue-only alias (13.9 KB < yt)

    int tid = threadIdx.x;
    int bl = blockIdx.x;
    int b = boff + bl;
    int lane = tid & 63, wid = tid >> 6;
    int fr = lane & 15, fq = lane >> 4;
    int g = wid & 1, ng = wid >> 1;               // conv2: mts {2g,2g+1}, rows {4ng..4ng+3}

    // ---- prologue: xpad zero + fill ----
    for (int i = tid; i < 3 * 34 * 34; i += 512) xpad[i] = 0.f;
    __syncthreads();
    for (int i = tid; i < 3072; i += 512) {
        int ch = i >> 10, rr = (i >> 5) & 31, cc = i & 31;
        xpad[(ch * 34 + rr + 1) * 34 + cc + 1] = x[(size_t)b * IW_ + i];
    }
    __syncthreads();

    // ---- leaf-invariant conv1 im2col B-frags (pool-window-in-lane mapping) ----
    short8 Bh[8];
#pragma unroll
    for (int i = 0; i < 8; ++i) {
        int Rg = i >> 2;
        int subrow = (i >> 1) & 1;
        int parity = i & 1;
        int prow = (wid * 2 + Rg) * 2 + subrow;   // 0..31
        int pcol = 2 * fr + parity;               // 0..31
#pragma unroll
        for (int j = 0; j < 8; ++j) {
            int k = fq * 8 + j;          // k = ic*9 + tap
            float xv = 0.f;
            if (k < 27) {
                int ic = k / 9;
                int tap = k - ic * 9;
                int dr = tap / 3, dc = tap - dr * 3;
                xv = xpad[(ic * 34 + prow + dr) * 34 + (pcol + dc)];
            }
            Bh[i][j] = (short)f2bf(xv);
        }
    }
    __syncthreads();
    {   // zero y plane (borders stay zero forever)
        uint4 z; z.x = z.y = z.z = z.w = 0u;
        for (int i = tid; i < YPLANE / 8; i += 512) ((uint4*)yt)[i] = z;
    }
    __syncthreads();

    f32x4 acc[2][4], oacc[2][4];
#pragma unroll
    for (int m = 0; m < 2; ++m)
#pragma unroll
        for (int rl = 0; rl < 4; ++rl) { acc[m][rl] = (f32x4)0.f; oacc[m][rl] = (f32x4)0.f; }

    for (int l = 0; l < 8; ++l) {
        // ---- async-stage this leaf's 72KB W2 chunk via global_load_lds (hides under conv1) ----
        {
            const char* wsrc = (const char*)(w2r + (size_t)l * WCH);
#pragma unroll
            for (int r = 0; r < 9; ++r) {
                int idx = r * 8 + wid;
                const char* gp = wsrc + idx * 1024 + lane * 16;
                __builtin_amdgcn_global_load_lds(
                    (const __attribute__((address_space(1))) uint*)gp,
                    (__attribute__((address_space(3))) uint*)((char*)wlds + idx * 1024),
                    16, 0, 0);
            }
        }

        // ---- conv1 phase: all 64 chans (4 mtiles), single-plane W1, in-lane pool ----
#pragma unroll
        for (int mtg = 0; mtg < 4; ++mtg) {
            short8 ah = *(const short8*)(w1fr + ((size_t)(l * 4 + mtg) * 64 + lane) * 8);
            f32x4 a1[8];
#pragma unroll
            for (int i = 0; i < 8; ++i) {
                f32x4 t = (f32x4)0.f;
                t = __builtin_amdgcn_mfma_f32_16x16x32_bf16(ah, Bh[i], t, 0, 0, 0);
                a1[i] = t;
            }
            float4 bias4 = *(const float4*)(cb1 + l * 64 + mtg * 16 + fq * 4);
            float bb[4] = {bias4.x, bias4.y, bias4.z, bias4.w};
#pragma unroll
            for (int Rg = 0; Rg < 2; ++Rg) {
                ushort hb[4];
#pragma unroll
                for (int j2 = 0; j2 < 4; ++j2) {
                    float m0 = fmaxf(fmaxf(a1[Rg * 4 + 0][j2], a1[Rg * 4 + 1][j2]),
                                     fmaxf(a1[Rg * 4 + 2][j2], a1[Rg * 4 + 3][j2]));
                    float v = fmaxf(m0 + bb[j2], 0.f);
                    hb[j2] = f2bf(v);
                }
                int pr = 2 * wid + Rg;
                int off = ((pr + 1) * 18 + (fr + 1)) * ICST + mtg * 16 + fq * 4;
                uint2 H;
                H.x = (uint)hb[0] | ((uint)hb[1] << 16);
                H.y = (uint)hb[2] | ((uint)hb[3] << 16);
                *(uint2*)&yt[off] = H;
            }
        }
        __syncthreads();   // drains vmcnt (gll complete) + y writes visible

        // ---- conv2 phase: dc-major, full K=64 (2 icc sub-chunks), input-row reuse ----
#pragma unroll
        for (int dc = 0; dc < 3; ++dc) {
#pragma unroll
            for (int icc = 0; icc < 2; ++icc) {
                short8 Ah[2][3];
#pragma unroll
                for (int dr = 0; dr < 3; ++dr) {
                    int tap = dr * 3 + dc;
#pragma unroll
                    for (int m = 0; m < 2; ++m) {
                        int mt = 2 * g + m;
                        Ah[m][dr] = *(const short8*)&wlds[(((icc * 9 + tap) * 4 + mt) * 64 + lane) * 8];
                    }
                }
#pragma unroll
                for (int rr = 0; rr < 6; ++rr) {
                    int off = ((4 * ng + rr) * 18 + (fr + dc)) * ICST + icc * 32 + fq * 8;
                    short8 bh = *(const short8*)(yt + off);
#pragma unroll
                    for (int dr = 0; dr < 3; ++dr) {
                        int rl = rr - dr;
                        if (rl >= 0 && rl < 4) {
#pragma unroll
                            for (int m = 0; m < 2; ++m) {
                                acc[m][rl] = __builtin_amdgcn_mfma_f32_16x16x32_bf16(Ah[m][dr], bh, acc[m][rl], 0, 0, 0);
                            }
                        }
                    }
                }
            }
        }
        {   // leaf epilogue: bias + relu + mixture accumulate
            float mx = mixw[(size_t)b * 8 + l];
#pragma unroll
            for (int m = 0; m < 2; ++m)
#pragma unroll
                for (int j = 0; j < 4; ++j) {
                    float bias = cb2[l * 64 + (2 * g + m) * 16 + fq * 4 + j];
#pragma unroll
                    for (int rl = 0; rl < 4; ++rl) {
                        float v = fmaxf(acc[m][rl][j] + bias, 0.f);
                        oacc[m][rl][j] = fmaf(mx, v, oacc[m][rl][j]);
                        acc[m][rl][j] = 0.f;
                    }
                }
        }
        __syncthreads();   // protect y + wlds before next leaf's gll/writes
    }

    // ---- fc epilogue: out[b][10] = fcw . out1 (block-local; no out1 in HBM) ----
    float pj[OUTW_];
#pragma unroll
    for (int j = 0; j < OUTW_; ++j) pj[j] = 0.f;
#pragma unroll
    for (int m = 0; m < 2; ++m)
#pragma unroll
        for (int rl = 0; rl < 4; ++rl)
#pragma unroll
            for (int jj = 0; jj < 4; ++jj) {
                int oc = (2 * g + m) * 16 + fq * 4 + jj;
                int pos = (4 * ng + rl) * 16 + fr;
                int e = oc * 256 + pos;
                const float4* fp = (const float4*)(fcwT + (size_t)e * 12);
                float4 f0 = fp[0], f1 = fp[1], f2 = fp[2];
                float v = oacc[m][rl][jj];
                pj[0] = fmaf(v, f0.x, pj[0]); pj[1] = fmaf(v, f0.y, pj[1]);
                pj[2] = fmaf(v, f0.z, pj[2]); pj[3] = fmaf(v, f0.w, pj[3]);
                pj[4] = fmaf(v, f1.x, pj[4]); pj[5] = fmaf(v, f1.y, pj[5]);
                pj[6] = fmaf(v, f1.z, pj[6]); pj[7] = fmaf(v, f1.w, pj[7]);
                pj[8] = fmaf(v, f2.x, pj[8]); pj[9] = fmaf(v, f2.y, pj[9]);
            }
    float* sred = (float*)smem;   // reuse LDS (after final barrier above)
#pragma unroll
    for (int j = 0; j < OUTW_; ++j) {
        float v = pj[j];
        for (int off = 32; off > 0; off >>= 1) v += __shfl_xor(v, off);
        if (lane == 0) sred[wid * OUTW_ + j] = v;
    }
    __syncthreads();
    if (tid < OUTW_) {
        float s = fcb[tid];
#pragma unroll
        for (int w = 0; w < 8; ++w) s += sred[w * OUTW_ + tid];
        out[(size_t)b * OUTW_ + tid] = s;
    }
}

extern "C" void kernel_launch(void* const* d_in, const int* in_sizes, int n_in,
                              void* d_out, int out_size, void* d_ws, size_t ws_size,
                              hipStream_t stream) {
    const float* x   = (const float*)d_in[0];
    const float* nw  = (const float*)d_in[1];
    const float* nb  = (const float*)d_in[2];
    const float* w1  = (const float*)d_in[3];
    const float* cb1 = (const float*)d_in[4];
    const float* w2  = (const float*)d_in[5];
    const float* cb2 = (const float*)d_in[6];
    const float* fcw = (const float*)d_in[7];
    const float* fcb = (const float*)d_in[8];
    float* out = (float*)d_out;

    float*  ws   = (float*)d_ws;
    float*  mix  = ws;                        // 2048 f
    ushort* w1fr = (ushort*)(mix + 2048);     // 16384 us (single RTN plane)
    ushort* w2r  = w1fr + 16384;              // 294912 us ([l][icc][tap][mt][lane][j8] single plane)
    float*  fcwT = (float*)(w2r + 294912);    // 196608 f ([e][12], j<10 data + pad)
    // total fixed: 2048*4 + 16384*2 + 294912*2 + 196608*4 = 1417216 B (< ws_size)

    k_prep<<<2240, 256, 0, stream>>>(w1, w1fr, w2, w2r, fcw, fcwT, x, nw, nb, mix);
    k_fused<<<B_, 512, 0, stream>>>(x, w1fr, cb1, w2r, cb2, mix, fcwT, fcb, out, 0);
}

// Round 19
// 82.380 us; speedup vs baseline: 1.3300x; 1.3300x over previous
//
#include <hip/hip_runtime.h>
#include <cstdint>
#include <cstddef>

#define B_ 256
#define IW_ 3072
#define L_ 8
#define NN_ 7
#define FCIN_ 16384
#define OUTW_ 10
#define ICST 40            // ushorts per (row,col) cell: 32 ic + 8 pad
#define YPLANE (324 * ICST)   // 12960 us = 25.9 KB per buffer

typedef short short8 __attribute__((ext_vector_type(8)));
typedef float f32x4 __attribute__((ext_vector_type(4)));

__device__ __forceinline__ ushort f2bf(float x) {
    uint u = __float_as_uint(x);
    return (ushort)((u + 0x7fffu + ((u >> 16) & 1u)) >> 16);
}
__device__ __forceinline__ float bf2f(ushort b) { return __uint_as_float(((uint)b) << 16); }

// ---------- merged prep: [0,64) w1 repack | [64,1216) w2 repack | [1216,1472) mixture ----------
__global__ __launch_bounds__(256) void k_prep(const float* __restrict__ w1, ushort* __restrict__ w1fr,
                                              const float* __restrict__ w2, ushort* __restrict__ w2r,
                                              const float* __restrict__ x, const float* __restrict__ nw,
                                              const float* __restrict__ nb, float* __restrict__ mix) {
    int blk = blockIdx.x;
    if (blk < 64) {
        // conv1 weights -> frag-linear single RTN plane: [l8][mt4][lane64][j8]
        int i = blk * 256 + threadIdx.x;
        int j    = i & 7;
        int lane = (i >> 3) & 63;
        int mt   = (i >> 9) & 3;
        int l    = i >> 11;
        int fr = lane & 15, fq = lane >> 4;
        int oc = mt * 16 + fr;
        int k = fq * 8 + j;
        float w = (k < 27) ? w1[(size_t)(l * 64 + oc) * 27 + k] : 0.f;
        w1fr[i] = f2bf(w);
        return;
    }
    if (blk < 1216) {
        // conv2 weights -> [l8][icc2][tap9][mt4][lane64][j8], single RTN bf16 plane
        int i = (blk - 64) * 256 + threadIdx.x;
        int j     = i & 7;
        int lane  = (i >> 3) & 63;
        int mt    = (i >> 9) & 3;
        int tap   = (i >> 11) % 9;
        int icc   = (i / 18432) & 1;
        int l     = i / 36864;
        int fr = lane & 15, fq = lane >> 4;
        int oc = mt * 16 + fr;
        int ic = icc * 32 + fq * 8 + j;
        float w = w2[(((size_t)l * 64 + oc) * 64 + ic) * 9 + tap];
        w2r[i] = f2bf(w);
        return;
    }
    // mixture
    __shared__ float red[4 * NN_];
    __shared__ float bes[NN_];
    int b = blk - 1216, tid = threadIdx.x;
    const float* xb = x + (size_t)b * IW_;
    float p[NN_];
#pragma unroll
    for (int n = 0; n < NN_; ++n) p[n] = 0.f;
    for (int i = tid; i < IW_; i += 256) {
        float xv = xb[i];
#pragma unroll
        for (int n = 0; n < NN_; ++n) p[n] = fmaf(xv, nw[n * IW_ + i], p[n]);
    }
#pragma unroll
    for (int n = 0; n < NN_; ++n) {
        float v = p[n];
        for (int off = 32; off > 0; off >>= 1) v += __shfl_xor(v, off);
        if ((tid & 63) == 0) red[(tid >> 6) * NN_ + n] = v;
    }
    __syncthreads();
    if (tid < NN_) {
        float s = red[tid] + red[NN_ + tid] + red[2 * NN_ + tid] + red[3 * NN_ + tid] + nb[tid];
        bes[tid] = 1.f / (1.f + expf(-s));
    }
    __syncthreads();
    if (tid < L_) {
        int leaf = tid;
        float b0 = bes[0];
        float t0 = ((leaf >> 2) & 1) ? b0 : 1.f - b0;
        float b1v = bes[1 + ((leaf >> 2) & 1)];
        float t1 = ((leaf >> 1) & 1) ? b1v : 1.f - b1v;
        float b2v = bes[3 + ((leaf >> 1) & 3)];
        float t2 = (leaf & 1) ? b2v : 1.f - b2v;
        mix[b * L_ + leaf] = t0 * t1 * t2;
    }
}

// ---------- fused conv1/conv2: y double-buffer, A-frags from global, 1 barrier/step ----------
// block = sample (grid 256 = 1/CU), 512 thr / 8 waves, 16 icc-steps.
// Step s: conv1(s+1) -> ybuf[(s+1)&1]  ||  conv2(s) <- ybuf[s&1] (A via global_load_dwordx4,
// L1/L2-broadcast) -> one barrier. conv1 and conv2 are fully independent inside the region
// (different y buffers, disjoint pipes: conv1 MFMA/VALU vs conv2 DS/L1/MFMA) -> compiler
// interleaves; DS pipe only carries y reads+writes (A stream moved to TA/L1).
__global__ __launch_bounds__(512, 1) void k_fused(const float* __restrict__ x,
                                                  const ushort* __restrict__ w1fr,
                                                  const float* __restrict__ cb1,
                                                  const ushort* __restrict__ w2r,
                                                  const float* __restrict__ cb2, const float* __restrict__ mixw,
                                                  float* __restrict__ out1, int boff) {
    __shared__ __align__(16) ushort smem[2 * YPLANE];   // ybuf0 | ybuf1 = 51.8 KB
    float* xpad = (float*)smem;                          // prologue-only alias (13.9 KB)

    int tid = threadIdx.x;
    int bl = blockIdx.x;
    int b = boff + bl;
    int lane = tid & 63, wid = tid >> 6;
    int fr = lane & 15, fq = lane >> 4;
    int g = wid & 1, ng = wid >> 1;               // conv2: mts {2g,2g+1}, rows {4ng..4ng+3}

    // ---- prologue: xpad zero + fill ----
    for (int i = tid; i < 3 * 34 * 34; i += 512) xpad[i] = 0.f;
    __syncthreads();
    for (int i = tid; i < 3072; i += 512) {
        int ch = i >> 10, rr = (i >> 5) & 31, cc = i & 31;
        xpad[(ch * 34 + rr + 1) * 34 + cc + 1] = x[(size_t)b * IW_ + i];
    }
    __syncthreads();

    // ---- leaf-invariant conv1 im2col B-frags (pool-window-in-lane mapping) ----
    short8 Bh[8];
#pragma unroll
    for (int i = 0; i < 8; ++i) {
        int Rg = i >> 2;
        int subrow = (i >> 1) & 1;
        int parity = i & 1;
        int prow = (wid * 2 + Rg) * 2 + subrow;   // 0..31
        int pcol = 2 * fr + parity;               // 0..31
#pragma unroll
        for (int j = 0; j < 8; ++j) {
            int k = fq * 8 + j;          // k = ic*9 + tap
            float xv = 0.f;
            if (k < 27) {
                int ic = k / 9;
                int tap = k - ic * 9;
                int dr = tap / 3, dc = tap - dr * 3;
                xv = xpad[(ic * 34 + prow + dr) * 34 + (pcol + dc)];
            }
            Bh[i][j] = (short)f2bf(xv);
        }
    }
    __syncthreads();
    {   // zero BOTH y planes (borders stay zero forever)
        uint4 z; z.x = z.y = z.z = z.w = 0u;
        for (int i = tid; i < (2 * YPLANE) / 8; i += 512) ((uint4*)smem)[i] = z;
    }
    __syncthreads();

    f32x4 acc[2][4], oacc[2][4];
#pragma unroll
    for (int m = 0; m < 2; ++m)
#pragma unroll
        for (int rl = 0; rl < 4; ++rl) { acc[m][rl] = (f32x4)0.f; oacc[m][rl] = (f32x4)0.f; }

    // conv1(s): 32 chans (2 mtiles) of step s's (l,icc) chunk -> ybuf[s&1]
    auto CONV1 = [&](int s) {
        int l = s >> 1, icc = s & 1;
        ushort* yt = smem + (size_t)(s & 1) * YPLANE;
#pragma unroll
        for (int mt2 = 0; mt2 < 2; ++mt2) {
            int mtg = icc * 2 + mt2;
            short8 ah = *(const short8*)(w1fr + ((size_t)(l * 4 + mtg) * 64 + lane) * 8);
            f32x4 a1[8];
#pragma unroll
            for (int i = 0; i < 8; ++i) {
                f32x4 t = (f32x4)0.f;
                t = __builtin_amdgcn_mfma_f32_16x16x32_bf16(ah, Bh[i], t, 0, 0, 0);
                a1[i] = t;
            }
            float4 bias4 = *(const float4*)(cb1 + l * 64 + mtg * 16 + fq * 4);
            float bb[4] = {bias4.x, bias4.y, bias4.z, bias4.w};
#pragma unroll
            for (int Rg = 0; Rg < 2; ++Rg) {
                ushort hb[4];
#pragma unroll
                for (int j2 = 0; j2 < 4; ++j2) {
                    float m0 = fmaxf(fmaxf(a1[Rg * 4 + 0][j2], a1[Rg * 4 + 1][j2]),
                                     fmaxf(a1[Rg * 4 + 2][j2], a1[Rg * 4 + 3][j2]));
                    float v = fmaxf(m0 + bb[j2], 0.f);
                    hb[j2] = f2bf(v);
                }
                int pr = 2 * wid + Rg;
                int off = ((pr + 1) * 18 + (fr + 1)) * ICST + mt2 * 16 + fq * 4;
                uint2 H;
                H.x = (uint)hb[0] | ((uint)hb[1] << 16);
                H.y = (uint)hb[2] | ((uint)hb[3] << 16);
                *(uint2*)&yt[off] = H;
            }
        }
    };

    // conv2(s): reads ybuf[s&1]; A-frags straight from global (L1/L2-broadcast)
    auto CONV2 = [&](int s) {
        int l = s >> 1, icc = s & 1;
        const ushort* yt = smem + (size_t)(s & 1) * YPLANE;
        const ushort* wbase = w2r + (size_t)(l * 2 + icc) * 18432;
#pragma unroll
        for (int dc = 0; dc < 3; ++dc) {
            short8 Ah[2][3];
#pragma unroll
            for (int dr = 0; dr < 3; ++dr) {
                int tap = dr * 3 + dc;
#pragma unroll
                for (int m = 0; m < 2; ++m) {
                    int mt = 2 * g + m;
                    Ah[m][dr] = *(const short8*)(wbase + ((size_t)(tap * 4 + mt) * 64 + lane) * 8);
                }
            }
#pragma unroll
            for (int rr = 0; rr < 6; ++rr) {
                int off = ((4 * ng + rr) * 18 + (fr + dc)) * ICST + fq * 8;
                short8 bh = *(const short8*)(yt + off);
#pragma unroll
                for (int dr = 0; dr < 3; ++dr) {
                    int rl = rr - dr;
                    if (rl >= 0 && rl < 4) {
#pragma unroll
                        for (int m = 0; m < 2; ++m) {
                            acc[m][rl] = __builtin_amdgcn_mfma_f32_16x16x32_bf16(Ah[m][dr], bh, acc[m][rl], 0, 0, 0);
                        }
                    }
                }
            }
        }
        if (icc) {  // leaf epilogue: bias + relu + mixture accumulate
            float mx = mixw[(size_t)b * 8 + l];
#pragma unroll
            for (int m = 0; m < 2; ++m)
#pragma unroll
                for (int j = 0; j < 4; ++j) {
                    float bias = cb2[l * 64 + (2 * g + m) * 16 + fq * 4 + j];
#pragma unroll
                    for (int rl = 0; rl < 4; ++rl) {
                        float v = fmaxf(acc[m][rl][j] + bias, 0.f);
                        oacc[m][rl][j] = fmaf(mx, v, oacc[m][rl][j]);
                        acc[m][rl][j] = 0.f;
                    }
                }
        }
    };

    // ---- software pipeline: conv1(s+1) || conv2(s), one barrier per step ----
    CONV1(0);
    __syncthreads();
    for (int s = 0; s < 16; ++s) {
        if (s < 15) CONV1(s + 1);
        CONV2(s);
        __syncthreads();
    }

    // ---- store out1 [bl][64 oc][256 pos] fp32 ----
#pragma unroll
    for (int m = 0; m < 2; ++m)
#pragma unroll
        for (int rl = 0; rl < 4; ++rl)
#pragma unroll
            for (int j = 0; j < 4; ++j) {
                int oc = (2 * g + m) * 16 + fq * 4 + j;
                int pos = (4 * ng + rl) * 16 + fr;
                out1[((size_t)bl * 64 + oc) * 256 + pos] = oacc[m][rl][j];
            }
}

// ---------- fc: [bc][16384] @ [10][16384]^T + b ----------
__global__ __launch_bounds__(256) void k_fc(const float* __restrict__ out1, const float* __restrict__ fcw,
                                            const float* __restrict__ fcb, float* __restrict__ out, int boff) {
    __shared__ float red[4][OUTW_];
    int tid = threadIdx.x;
    int bl = blockIdx.x;
    const float4* flat = (const float4*)(out1 + (size_t)bl * FCIN_);
    float pj[OUTW_];
#pragma unroll
    for (int j = 0; j < OUTW_; ++j) pj[j] = 0.f;
    for (int i = tid; i < FCIN_ / 4; i += 256) {
        float4 v = flat[i];
#pragma unroll
        for (int j = 0; j < OUTW_; ++j) {
            float4 w = ((const float4*)(fcw + (size_t)j * FCIN_))[i];
            pj[j] += v.x * w.x + v.y * w.y + v.z * w.z + v.w * w.w;
        }
    }
#pragma unroll
    for (int j = 0; j < OUTW_; ++j) {
        float v = pj[j];
        for (int off = 32; off > 0; off >>= 1) v += __shfl_xor(v, off);
        if ((tid & 63) == 0) red[tid >> 6][j] = v;
    }
    __syncthreads();
    if (tid < OUTW_) {
        float s = red[0][tid] + red[1][tid] + red[2][tid] + red[3][tid] + fcb[tid];
        out[(size_t)(boff + bl) * OUTW_ + tid] = s;
    }
}

extern "C" void kernel_launch(void* const* d_in, const int* in_sizes, int n_in,
                              void* d_out, int out_size, void* d_ws, size_t ws_size,
                              hipStream_t stream) {
    const float* x   = (const float*)d_in[0];
    const float* nw  = (const float*)d_in[1];
    const float* nb  = (const float*)d_in[2];
    const float* w1  = (const float*)d_in[3];
    const float* cb1 = (const float*)d_in[4];
    const float* w2  = (const float*)d_in[5];
    const float* cb2 = (const float*)d_in[6];
    const float* fcw = (const float*)d_in[7];
    const float* fcb = (const float*)d_in[8];
    float* out = (float*)d_out;

    float*  ws   = (float*)d_ws;
    float*  mix  = ws;                        // 2048 f
    ushort* w1fr = (ushort*)(mix + 2048);     // 16384 us (single RTN plane)
    ushort* w2r  = w1fr + 16384;              // 294912 us ([l][icc][tap][mt][lane][j8] single plane)
    float*  out1 = (float*)(w2r + 294912);    // Bc * 16384 f

    // fixed bytes: 2048*4 + 16384*2 + 294912*2 = 630784; out1 per sample = 65536 B
    long avail = (long)ws_size - 630784L;
    int Bc = (int)(avail / 65536L);
    if (Bc > B_) Bc = B_;
    if (Bc < 1) Bc = 1;

    k_prep<<<1472, 256, 0, stream>>>(w1, w1fr, w2, w2r, x, nw, nb, mix);

    for (int boff = 0; boff < B_; boff += Bc) {
        int bc = (B_ - boff < Bc) ? (B_ - boff) : Bc;
        k_fused<<<bc, 512, 0, stream>>>(x, w1fr, cb1, w2r, cb2, mix, out1, boff);
        k_fc<<<bc, 256, 0, stream>>>(out1, fcw, fcb, out, boff);
    }
}

// Round 20
// 80.301 us; speedup vs baseline: 1.3644x; 1.0259x over previous
//
#include <hip/hip_runtime.h>
#include <cstdint>
#include <cstddef>

#define B_ 256
#define IW_ 3072
#define L_ 8
#define NN_ 7
#define FCIN_ 16384
#define OUTW_ 10
#define ICST 40            // ushorts per (row,col) cell: 32 ic + 8 pad
#define YPLANE (324 * ICST)   // 12960 us = 25.9 KB per buffer

typedef short short8 __attribute__((ext_vector_type(8)));
typedef float f32x4 __attribute__((ext_vector_type(4)));

__device__ __forceinline__ ushort f2bf(float x) {
    uint u = __float_as_uint(x);
    return (ushort)((u + 0x7fffu + ((u >> 16) & 1u)) >> 16);
}
__device__ __forceinline__ float bf2f(ushort b) { return __uint_as_float(((uint)b) << 16); }

// ---------- merged prep: [0,64) w1 repack | [64,1216) w2 repack | [1216,1472) mixture ----------
__global__ __launch_bounds__(256) void k_prep(const float* __restrict__ w1, ushort* __restrict__ w1fr,
                                              const float* __restrict__ w2, ushort* __restrict__ w2r,
                                              const float* __restrict__ x, const float* __restrict__ nw,
                                              const float* __restrict__ nb, float* __restrict__ mix) {
    int blk = blockIdx.x;
    if (blk < 64) {
        // conv1 weights -> frag-linear single RTN plane: [l8][mt4][lane64][j8]
        int i = blk * 256 + threadIdx.x;
        int j    = i & 7;
        int lane = (i >> 3) & 63;
        int mt   = (i >> 9) & 3;
        int l    = i >> 11;
        int fr = lane & 15, fq = lane >> 4;
        int oc = mt * 16 + fr;
        int k = fq * 8 + j;
        float w = (k < 27) ? w1[(size_t)(l * 64 + oc) * 27 + k] : 0.f;
        w1fr[i] = f2bf(w);
        return;
    }
    if (blk < 1216) {
        // conv2 weights -> [l8][icc2][tap9][mt4][lane64][j8], single RTN bf16 plane
        int i = (blk - 64) * 256 + threadIdx.x;
        int j     = i & 7;
        int lane  = (i >> 3) & 63;
        int mt    = (i >> 9) & 3;
        int tap   = (i >> 11) % 9;
        int icc   = (i / 18432) & 1;
        int l     = i / 36864;
        int fr = lane & 15, fq = lane >> 4;
        int oc = mt * 16 + fr;
        int ic = icc * 32 + fq * 8 + j;
        float w = w2[(((size_t)l * 64 + oc) * 64 + ic) * 9 + tap];
        w2r[i] = f2bf(w);
        return;
    }
    // mixture
    __shared__ float red[4 * NN_];
    __shared__ float bes[NN_];
    int b = blk - 1216, tid = threadIdx.x;
    const float* xb = x + (size_t)b * IW_;
    float p[NN_];
#pragma unroll
    for (int n = 0; n < NN_; ++n) p[n] = 0.f;
    for (int i = tid; i < IW_; i += 256) {
        float xv = xb[i];
#pragma unroll
        for (int n = 0; n < NN_; ++n) p[n] = fmaf(xv, nw[n * IW_ + i], p[n]);
    }
#pragma unroll
    for (int n = 0; n < NN_; ++n) {
        float v = p[n];
        for (int off = 32; off > 0; off >>= 1) v += __shfl_xor(v, off);
        if ((tid & 63) == 0) red[(tid >> 6) * NN_ + n] = v;
    }
    __syncthreads();
    if (tid < NN_) {
        float s = red[tid] + red[NN_ + tid] + red[2 * NN_ + tid] + red[3 * NN_ + tid] + nb[tid];
        bes[tid] = 1.f / (1.f + expf(-s));
    }
    __syncthreads();
    if (tid < L_) {
        int leaf = tid;
        float b0 = bes[0];
        float t0 = ((leaf >> 2) & 1) ? b0 : 1.f - b0;
        float b1v = bes[1 + ((leaf >> 2) & 1)];
        float t1 = ((leaf >> 1) & 1) ? b1v : 1.f - b1v;
        float b2v = bes[3 + ((leaf >> 1) & 3)];
        float t2 = (leaf & 1) ? b2v : 1.f - b2v;
        mix[b * L_ + leaf] = t0 * t1 * t2;
    }
}

// ---------- fused conv1/conv2: 1024 thr (16 waves = 4 waves/SIMD at 1 block/CU) ----------
// block = sample. Per-wave tiles halved vs R19: conv1 = 1 pooled row (Bh[4], 16 regs),
// conv2 = 1 mtile x 4 rows (acc+oacc = 32 regs) -> total ~112 regs fits the 128 cap of
// 4 waves/SIMD. Same chip-level work; 2x TLP covers the latency that intra-wave
// restructuring couldn't. y double-buffer + A-frags from global (L1), 1 barrier/step.
__global__ __launch_bounds__(1024, 1) void k_fused(const float* __restrict__ x,
                                                   const ushort* __restrict__ w1fr,
                                                   const float* __restrict__ cb1,
                                                   const ushort* __restrict__ w2r,
                                                   const float* __restrict__ cb2, const float* __restrict__ mixw,
                                                   float* __restrict__ out1, int boff) {
    __shared__ __align__(16) ushort smem[2 * YPLANE];   // ybuf0 | ybuf1 = 51.8 KB
    float* xpad = (float*)smem;                          // prologue-only alias (13.9 KB)

    int tid = threadIdx.x;
    int bl = blockIdx.x;
    int b = boff + bl;
    int lane = tid & 63, wid = tid >> 6;                 // wid 0..15
    int fr = lane & 15, fq = lane >> 4;
    int mt = wid >> 2, ng = wid & 3;                     // conv2: mtile mt, rows {4ng..4ng+3}

    // ---- prologue: xpad zero + fill ----
    for (int i = tid; i < 3 * 34 * 34; i += 1024) xpad[i] = 0.f;
    __syncthreads();
    for (int i = tid; i < 3072; i += 1024) {
        int ch = i >> 10, rr = (i >> 5) & 31, cc = i & 31;
        xpad[(ch * 34 + rr + 1) * 34 + cc + 1] = x[(size_t)b * IW_ + i];
    }
    __syncthreads();

    // ---- leaf-invariant conv1 im2col B-frags: wave owns pooled row wid ----
    short8 Bh[4];
#pragma unroll
    for (int i = 0; i < 4; ++i) {
        int subrow = i >> 1;
        int parity = i & 1;
        int prow = wid * 2 + subrow;          // 0..31
        int pcol = 2 * fr + parity;           // 0..31
#pragma unroll
        for (int j = 0; j < 8; ++j) {
            int k = fq * 8 + j;               // k = ic*9 + tap
            float xv = 0.f;
            if (k < 27) {
                int ic = k / 9;
                int tap = k - ic * 9;
                int dr = tap / 3, dc = tap - dr * 3;
                xv = xpad[(ic * 34 + prow + dr) * 34 + (pcol + dc)];
            }
            Bh[i][j] = (short)f2bf(xv);
        }
    }
    __syncthreads();
    {   // zero BOTH y planes (borders stay zero forever)
        uint4 z; z.x = z.y = z.z = z.w = 0u;
        for (int i = tid; i < (2 * YPLANE) / 8; i += 1024) ((uint4*)smem)[i] = z;
    }
    __syncthreads();

    f32x4 acc[4], oacc[4];
#pragma unroll
    for (int rl = 0; rl < 4; ++rl) { acc[rl] = (f32x4)0.f; oacc[rl] = (f32x4)0.f; }

    // conv1(s): 32 chans (2 mtiles) of step s's (l,icc) chunk for pooled row wid -> ybuf[s&1]
    auto CONV1 = [&](int s) {
        int l = s >> 1, icc = s & 1;
        ushort* yt = smem + (size_t)(s & 1) * YPLANE;
#pragma unroll
        for (int mt2 = 0; mt2 < 2; ++mt2) {
            int mtg = icc * 2 + mt2;
            short8 ah = *(const short8*)(w1fr + ((size_t)(l * 4 + mtg) * 64 + lane) * 8);
            f32x4 a1[4];
#pragma unroll
            for (int i = 0; i < 4; ++i) {
                f32x4 t = (f32x4)0.f;
                t = __builtin_amdgcn_mfma_f32_16x16x32_bf16(ah, Bh[i], t, 0, 0, 0);
                a1[i] = t;
            }
            float4 bias4 = *(const float4*)(cb1 + l * 64 + mtg * 16 + fq * 4);
            float bb[4] = {bias4.x, bias4.y, bias4.z, bias4.w};
            ushort hb[4];
#pragma unroll
            for (int j2 = 0; j2 < 4; ++j2) {
                float m0 = fmaxf(fmaxf(a1[0][j2], a1[1][j2]), fmaxf(a1[2][j2], a1[3][j2]));
                float v = fmaxf(m0 + bb[j2], 0.f);
                hb[j2] = f2bf(v);
            }
            int off = ((wid + 1) * 18 + (fr + 1)) * ICST + mt2 * 16 + fq * 4;
            uint2 H;
            H.x = (uint)hb[0] | ((uint)hb[1] << 16);
            H.y = (uint)hb[2] | ((uint)hb[3] << 16);
            *(uint2*)&yt[off] = H;
        }
    };

    // conv2(s): reads ybuf[s&1]; A-frags straight from global (L1/L2-broadcast)
    auto CONV2 = [&](int s) {
        int l = s >> 1, icc = s & 1;
        const ushort* yt = smem + (size_t)(s & 1) * YPLANE;
        const ushort* wbase = w2r + (size_t)(l * 2 + icc) * 18432;
#pragma unroll
        for (int dc = 0; dc < 3; ++dc) {
            short8 Ah[3];
#pragma unroll
            for (int dr = 0; dr < 3; ++dr) {
                int tap = dr * 3 + dc;
                Ah[dr] = *(const short8*)(wbase + ((size_t)(tap * 4 + mt) * 64 + lane) * 8);
            }
#pragma unroll
            for (int rr = 0; rr < 6; ++rr) {
                int off = ((4 * ng + rr) * 18 + (fr + dc)) * ICST + fq * 8;
                short8 bh = *(const short8*)(yt + off);
#pragma unroll
                for (int dr = 0; dr < 3; ++dr) {
                    int rl = rr - dr;
                    if (rl >= 0 && rl < 4) {
                        acc[rl] = __builtin_amdgcn_mfma_f32_16x16x32_bf16(Ah[dr], bh, acc[rl], 0, 0, 0);
                    }
                }
            }
        }
        if (icc) {  // leaf epilogue: bias + relu + mixture accumulate
            float mx = mixw[(size_t)b * 8 + l];
#pragma unroll
            for (int j = 0; j < 4; ++j) {
                float bias = cb2[l * 64 + mt * 16 + fq * 4 + j];
#pragma unroll
                for (int rl = 0; rl < 4; ++rl) {
                    float v = fmaxf(acc[rl][j] + bias, 0.f);
                    oacc[rl][j] = fmaf(mx, v, oacc[rl][j]);
                    acc[rl][j] = 0.f;
                }
            }
        }
    };

    // ---- software pipeline: conv1(s+1) || conv2(s), one barrier per step ----
    CONV1(0);
    __syncthreads();
    for (int s = 0; s < 16; ++s) {
        if (s < 15) CONV1(s + 1);
        CONV2(s);
        __syncthreads();
    }

    // ---- store out1 [bl][64 oc][256 pos] fp32 ----
#pragma unroll
    for (int rl = 0; rl < 4; ++rl)
#pragma unroll
        for (int j = 0; j < 4; ++j) {
            int oc = mt * 16 + fq * 4 + j;
            int pos = (4 * ng + rl) * 16 + fr;
            out1[((size_t)bl * 64 + oc) * 256 + pos] = oacc[rl][j];
        }
}

// ---------- fc: [bc][16384] @ [10][16384]^T + b ----------
__global__ __launch_bounds__(256) void k_fc(const float* __restrict__ out1, const float* __restrict__ fcw,
                                            const float* __restrict__ fcb, float* __restrict__ out, int boff) {
    __shared__ float red[4][OUTW_];
    int tid = threadIdx.x;
    int bl = blockIdx.x;
    const float4* flat = (const float4*)(out1 + (size_t)bl * FCIN_);
    float pj[OUTW_];
#pragma unroll
    for (int j = 0; j < OUTW_; ++j) pj[j] = 0.f;
    for (int i = tid; i < FCIN_ / 4; i += 256) {
        float4 v = flat[i];
#pragma unroll
        for (int j = 0; j < OUTW_; ++j) {
            float4 w = ((const float4*)(fcw + (size_t)j * FCIN_))[i];
            pj[j] += v.x * w.x + v.y * w.y + v.z * w.z + v.w * w.w;
        }
    }
#pragma unroll
    for (int j = 0; j < OUTW_; ++j) {
        float v = pj[j];
        for (int off = 32; off > 0; off >>= 1) v += __shfl_xor(v, off);
        if ((tid & 63) == 0) red[tid >> 6][j] = v;
    }
    __syncthreads();
    if (tid < OUTW_) {
        float s = red[0][tid] + red[1][tid] + red[2][tid] + red[3][tid] + fcb[tid];
        out[(size_t)(boff + bl) * OUTW_ + tid] = s;
    }
}

extern "C" void kernel_launch(void* const* d_in, const int* in_sizes, int n_in,
                              void* d_out, int out_size, void* d_ws, size_t ws_size,
                              hipStream_t stream) {
    const float* x   = (const float*)d_in[0];
    const float* nw  = (const float*)d_in[1];
    const float* nb  = (const float*)d_in[2];
    const float* w1  = (const float*)d_in[3];
    const float* cb1 = (const float*)d_in[4];
    const float* w2  = (const float*)d_in[5];
    const float* cb2 = (const float*)d_in[6];
    const float* fcw = (const float*)d_in[7];
    const float* fcb = (const float*)d_in[8];
    float* out = (float*)d_out;

    float*  ws   = (float*)d_ws;
    float*  mix  = ws;                        // 2048 f
    ushort* w1fr = (ushort*)(mix + 2048);     // 16384 us (single RTN plane)
    ushort* w2r  = w1fr + 16384;              // 294912 us ([l][icc][tap][mt][lane][j8] single plane)
    float*  out1 = (float*)(w2r + 294912);    // Bc * 16384 f

    // fixed bytes: 2048*4 + 16384*2 + 294912*2 = 630784; out1 per sample = 65536 B
    long avail = (long)ws_size - 630784L;
    int Bc = (int)(avail / 65536L);
    if (Bc > B_) Bc = B_;
    if (Bc < 1) Bc = 1;

    k_prep<<<1472, 256, 0, stream>>>(w1, w1fr, w2, w2r, x, nw, nb, mix);

    for (int boff = 0; boff < B_; boff += Bc) {
        int bc = (B_ - boff < Bc) ? (B_ - boff) : Bc;
        k_fused<<<bc, 1024, 0, stream>>>(x, w1fr, cb1, w2r, cb2, mix, out1, boff);
        k_fc<<<bc, 256, 0, stream>>>(out1, fcw, fcb, out, boff);
    }
}